// Round 11
// baseline (71.006 us; speedup 1.0000x reference)
//
#include <hip/hip_runtime.h>

#define DDIM 128
#define ACC_BLOCKS 2048
#define NHALF (ACC_BLOCKS * 4 * 2)   // 16384 half-walkers (2 per wave)
#define RED_BLOCKS 64

typedef unsigned int uint;
typedef unsigned short ushort;
typedef __attribute__((ext_vector_type(8))) short bf16x8;
typedef __attribute__((ext_vector_type(4))) float f32x4;

static __device__ __forceinline__ ushort f2bf(float x) {
    uint u = __float_as_uint(x);
    u += 0x7fffu + ((u >> 16) & 1u);   // RTN-even
    return (ushort)(u >> 16);
}
static __device__ __forceinline__ float bflo(uint u) { return __uint_as_float(u << 16); }
static __device__ __forceinline__ float bfhi(uint u) { return __uint_as_float(u & 0xffff0000u); }

// ---------------- Kernel 0: fused prep (rowptr + item stream + zrow + done) ----------------
// Node i's stream slot = rowptr[i]+i (Wh row, flush iff degree 0); edge x's slot
// = x + segs[x] + 1 (Mh row, flush iff last edge of its node). All derivable
// from segs boundaries in one edge-parallel pass — no rowptr dependency.
__global__ __launch_bounds__(256) void prep(
    const int* __restrict__ segs,
    const int* __restrict__ node_ids,
    const int* __restrict__ neighbor_ids,
    int* __restrict__ rowptr,
    int* __restrict__ items,
    int* __restrict__ done,
    float* __restrict__ zrow,
    int N, int E, int whoff, int mhoff, int zpad)
{
    const int x = blockIdx.x * blockDim.x + threadIdx.x;
    if (x == 0) *done = 0;
    if (x < 64) zrow[x] = 0.f;            // 256 B zero row (pad target)
    if (x >= E) return;

    const int sc = segs[x];
    const int sp = (x == 0) ? -1 : segs[x - 1];
    const int sn = (x + 1 < E) ? segs[x + 1] : N;   // sentinel > any node id

    // edge item
    items[x + sc + 1] = (mhoff + neighbor_ids[x] * 256) | ((sn != sc) ? (int)0x80000000 : 0);

    // boundary nodes (sp, sc]: rowptr = x; Wh item; flush iff i < sc (degree 0)
    for (int i = sp + 1; i <= sc; ++i) {
        rowptr[i] = x;
        items[x + i] = (whoff + node_ids[i] * 256) | ((i < sc) ? (int)0x80000000 : 0);
    }
    if (x == E - 1) {
        for (int i = sc + 1; i <= N; ++i) {
            rowptr[i] = E;
            if (i < N) items[E + i] = (whoff + node_ids[i] * 256) | (int)0x80000000;
        }
#pragma unroll
        for (int q = 0; q < 16; ++q) items[N + E + q] = zpad;   // zero-row pad, no flush
    }
}

// ---------------- Kernel 1: MFMA precompute Wh/Mh + wstart table ----------------
static __device__ __forceinline__ bf16x8 load_frag8(const float* base) {
    const float4 p = *reinterpret_cast<const float4*>(base);
    const float4 q = *reinterpret_cast<const float4*>(base + 4);
    bf16x8 f;
    f[0] = (short)f2bf(p.x); f[1] = (short)f2bf(p.y);
    f[2] = (short)f2bf(p.z); f[3] = (short)f2bf(p.w);
    f[4] = (short)f2bf(q.x); f[5] = (short)f2bf(q.y);
    f[6] = (short)f2bf(q.z); f[7] = (short)f2bf(q.w);
    return f;
}

__global__ __launch_bounds__(256) void precompute_mfma(
    const float* __restrict__ impact,
    const float* __restrict__ W,
    const float* __restrict__ Mm,
    ushort* __restrict__ WhB,
    ushort* __restrict__ MhB,
    const int* __restrict__ rowptr,
    int* __restrict__ wstart,
    int T, int N, int K)
{
    // spare-thread work: half-walker start table (node-aligned, equal item spacing)
    const int gid = blockIdx.x * 256 + threadIdx.x;
    if (gid <= NHALF) {
        const int t = (int)(((long long)gid * K) / NHALF);
        int lo = 0, hi = N;
        while (lo < hi) {
            const int mid = (lo + hi) >> 1;
            if (rowptr[mid] + mid < t) lo = mid + 1; else hi = mid;
        }
        wstart[gid] = rowptr[lo] + lo;     // lo==N -> K
    }

    const int lane = threadIdx.x & 63;
    const int wv   = threadIdx.x >> 6;       // 0..3 -> d tiles {2wv, 2wv+1}
    const int t0   = blockIdx.x * 32;
    const int r16  = lane & 15;
    const int kg   = lane >> 4;              // 0..3

    bf16x8 A[2][4];
#pragma unroll
    for (int rt = 0; rt < 2; ++rt) {
        int t = t0 + rt * 16 + r16;
        if (t >= T) t = T - 1;               // clamp; writes masked below
        const float* abase = impact + (size_t)t * DDIM + kg * 8;
#pragma unroll
        for (int k0i = 0; k0i < 4; ++k0i)
            A[rt][k0i] = load_frag8(abase + k0i * 32);
    }

#pragma unroll
    for (int dti = 0; dti < 2; ++dti) {
        const int d0 = (wv * 2 + dti) * 16;
#pragma unroll
        for (int m = 0; m < 2; ++m) {
            const float* mat = (m == 0) ? W : Mm;
            ushort* out = (m == 0) ? WhB : MhB;
            const float* bbase = mat + (size_t)(d0 + r16) * DDIM + kg * 8;
            f32x4 acc0 = {0.f, 0.f, 0.f, 0.f};
            f32x4 acc1 = {0.f, 0.f, 0.f, 0.f};
#pragma unroll
            for (int k0i = 0; k0i < 4; ++k0i) {
                const bf16x8 b = load_frag8(bbase + k0i * 32);
                acc0 = __builtin_amdgcn_mfma_f32_16x16x32_bf16(A[0][k0i], b, acc0, 0, 0, 0);
                acc1 = __builtin_amdgcn_mfma_f32_16x16x32_bf16(A[1][k0i], b, acc1, 0, 0, 0);
            }
            const int dcol = d0 + r16;
#pragma unroll
            for (int r = 0; r < 4; ++r) {
                const int tr0 = t0 + kg * 4 + r;
                const int tr1 = tr0 + 16;
                if (tr0 < T) out[(size_t)tr0 * DDIM + dcol] = f2bf(acc0[r]);
                if (tr1 < T) out[(size_t)tr1 * DDIM + dcol] = f2bf(acc1[r]);
            }
        }
    }
}

// ---------------- Kernel 2: pair-gather item-stream accumulate ----------------
// Wave = 2 half-walkers: lanes 0-31 process stream A, lanes 32-63 stream B
// (both node-aligned). Lane holds uint2 = 4 bf16 features; ONE dwordx2 gather
// covers TWO rows (512 B). Item words scalar; flush via per-half lane masks
// under a wave-uniform __any branch. Imbalance padded with a zero row.
__global__ __launch_bounds__(256, 8) void accumulate_items(
    const char* __restrict__ tab,
    const int* __restrict__ items,
    const int* __restrict__ wstart,
    float* __restrict__ partials,
    int zpad)
{
    const int tid  = threadIdx.x;
    const int lane = tid & 63;
    const int wv   = __builtin_amdgcn_readfirstlane(tid >> 6);
    const int w    = blockIdx.x * 4 + wv;

    int kA        = __builtin_amdgcn_readfirstlane(wstart[2 * w]);
    const int kAe = __builtin_amdgcn_readfirstlane(wstart[2 * w + 1]);
    int kB        = kAe;
    const int kBe = __builtin_amdgcn_readfirstlane(wstart[2 * w + 2]);

    const bool isB  = lane >= 32;
    const uint vbase = (uint)(lane & 31) * 8u;

    float c0 = 0.f, c1 = 0.f, c2 = 0.f, c3 = 0.f;
    float a0 = 0.f, a1 = 0.f, a2 = 0.f, a3 = 0.f;

    while (kA < kAe || kB < kBe) {
        int wA[8], wB[8];
        if (kA + 8 <= kAe && kB + 8 <= kBe) {
#pragma unroll
            for (int j = 0; j < 8; ++j) { wA[j] = items[kA + j]; wB[j] = items[kB + j]; }
        } else {
#pragma unroll
            for (int j = 0; j < 8; ++j) {
                wA[j] = (kA + j < kAe) ? items[kA + j] : zpad;
                wB[j] = (kB + j < kBe) ? items[kB + j] : zpad;
            }
        }
        uint2 v[8];
#pragma unroll
        for (int j = 0; j < 8; ++j) {
            const uint off = ((uint)(isB ? wB[j] : wA[j]) & 0x7fffffffu) + vbase;
            v[j] = *reinterpret_cast<const uint2*>(tab + off);
        }
#pragma unroll
        for (int j = 0; j < 8; ++j) {
            c0 += bflo(v[j].x); c1 += bfhi(v[j].x);
            c2 += bflo(v[j].y); c3 += bfhi(v[j].y);
            const bool fA = wA[j] < 0;
            const bool fB = wB[j] < 0;
            if (__builtin_amdgcn_ballot_w64(1) && (fA || fB)) {   // uniform cond (fA,fB scalar)
                const bool myf = isB ? fB : fA;
                a0 += myf ? fmaxf(c0, 0.f) : 0.f;
                a1 += myf ? fmaxf(c1, 0.f) : 0.f;
                a2 += myf ? fmaxf(c2, 0.f) : 0.f;
                a3 += myf ? fmaxf(c3, 0.f) : 0.f;
                c0 = myf ? 0.f : c0;  c1 = myf ? 0.f : c1;
                c2 = myf ? 0.f : c2;  c3 = myf ? 0.f : c3;
            }
        }
        kA = min(kA + 8, kAe);
        kB = min(kB + 8, kBe);
    }
    // both halves end node-aligned -> c is 0 unless zero-padded adds (still 0);
    // relu(0)=0 safe.
    a0 += fmaxf(c0, 0.f); a1 += fmaxf(c1, 0.f);
    a2 += fmaxf(c2, 0.f); a3 += fmaxf(c3, 0.f);

    __shared__ float red[8][DDIM];
    *reinterpret_cast<float4*>(&red[wv * 2 + (isB ? 1 : 0)][(lane & 31) * 4]) =
        make_float4(a0, a1, a2, a3);
    __syncthreads();
    if (tid < DDIM) {
        float s = 0.f;
#pragma unroll
        for (int g = 0; g < 8; ++g) s += red[g][tid];
        partials[(size_t)blockIdx.x * DDIM + tid] = s;
    }
}

// ---------------- Kernel 3: reduce partials + last-block softmax ----------------
__global__ __launch_bounds__(256) void reduce_softmax(
    const float* __restrict__ partials, float* __restrict__ out2,
    float* __restrict__ out, int* __restrict__ done, int nb)
{
    const int tid = threadIdx.x;
    const int d = tid & (DDIM - 1);
    const int h = tid >> 7;                  // 0..1
    {
        const int rows = nb / RED_BLOCKS;    // 32
        const int r0 = blockIdx.x * rows;
        float s = 0.f;
        for (int r = r0 + h; r < r0 + rows; r += 2)
            s += partials[(size_t)r * DDIM + d];
        __shared__ float red[2][DDIM];
        red[h][d] = s;
        __syncthreads();
        if (tid < DDIM)
            out2[(size_t)blockIdx.x * DDIM + tid] = red[0][tid] + red[1][tid];
    }
    __threadfence();
    __shared__ int isLast;
    if (tid == 0) {
        const int v = atomicAdd(done, 1);
        isLast = (v == RED_BLOCKS - 1) ? 1 : 0;
    }
    __syncthreads();
    if (!isLast) return;
    __threadfence();                          // acquire

    float s = 0.f;
    for (int b = h; b < RED_BLOCKS; b += 2)
        s += out2[(size_t)b * DDIM + d];
    __shared__ float r2[2][DDIM];
    r2[h][d] = s;
    __syncthreads();

    __shared__ float vec[DDIM];
    __shared__ float tmp[DDIM];
    if (tid < DDIM) { const float v = r2[0][tid] + r2[1][tid]; vec[tid] = v; tmp[tid] = v; }
    __syncthreads();
    for (int o = 64; o > 0; o >>= 1) {
        if (tid < o) tmp[tid] = fmaxf(tmp[tid], tmp[tid + o]);
        __syncthreads();
    }
    const float mx = tmp[0];
    __syncthreads();
    float ev = 0.f;
    if (tid < DDIM) { ev = expf(vec[tid] - mx); tmp[tid] = ev; }
    __syncthreads();
    for (int o = 64; o > 0; o >>= 1) {
        if (tid < o) tmp[tid] += tmp[tid + o];
        __syncthreads();
    }
    if (tid < DDIM) out[tid] = ev / tmp[0];
}

extern "C" void kernel_launch(void* const* d_in, const int* in_sizes, int n_in,
                              void* d_out, int out_size, void* d_ws, size_t ws_size,
                              hipStream_t stream) {
    const float* impact        = (const float*)d_in[0];
    const float* W             = (const float*)d_in[1];
    const float* Mm            = (const float*)d_in[2];
    const int*   node_ids      = (const int*)d_in[3];
    const int*   neighbor_ids  = (const int*)d_in[4];
    const int*   neighbor_segs = (const int*)d_in[5];

    const int T = in_sizes[0] / DDIM;   // 10000
    const int N = in_sizes[3];          // 50000
    const int E = in_sizes[4];          // 800000
    const int K = N + E;

    char* ws = (char*)d_ws;
    size_t off = 0;
    const int whoff = (int)off;
    ushort* WhB = (ushort*)(ws + off);  off += (size_t)T * DDIM * sizeof(ushort);   // 2.56 MB
    const int mhoff = (int)off;
    ushort* MhB = (ushort*)(ws + off);  off += (size_t)T * DDIM * sizeof(ushort);   // 2.56 MB
    const int zoff = (int)off;
    float* zrow = (float*)(ws + off);   off += 64 * sizeof(float);                  // 256 B
    float* partials = (float*)(ws + off); off += (size_t)ACC_BLOCKS * DDIM * sizeof(float);
    float* part2    = (float*)(ws + off); off += (size_t)RED_BLOCKS * DDIM * sizeof(float);
    int*   rowptr   = (int*)(ws + off);   off += (size_t)(N + 1) * sizeof(int);
    int*   done     = (int*)(ws + off);   off += 256;
    off = (off + 255) & ~(size_t)255;
    int*   items    = (int*)(ws + off);   off += (size_t)(K + 16) * sizeof(int);
    int*   wstart   = (int*)(ws + off);   off += (size_t)(NHALF + 1) * sizeof(int);
    float* outf     = (float*)d_out;

    prep<<<(E + 255) / 256, 256, 0, stream>>>(
        neighbor_segs, node_ids, neighbor_ids, rowptr, items, done, zrow,
        N, E, whoff, mhoff, zoff);
    precompute_mfma<<<(T + 31) / 32, 256, 0, stream>>>(
        impact, W, Mm, WhB, MhB, rowptr, wstart, T, N, K);
    accumulate_items<<<ACC_BLOCKS, 256, 0, stream>>>(ws, items, wstart, partials, zoff);
    reduce_softmax<<<RED_BLOCKS, 256, 0, stream>>>(partials, part2, outf, done, ACC_BLOCKS);
}